// Round 1
// baseline (2081.384 us; speedup 1.0000x reference)
//
#include <hip/hip_runtime.h>
#include <hip/hip_bf16.h>

// MoEReadout: N=100000 atoms, IN_F=512, HID=512, OUT_F=256,
// 6 routed experts (top-2 gated by softmax over species-embedding router)
// + 2 shared experts (always on). Output fp32 [N, 256].
//
// Structure:
//  k_cvt_w1 / k_cvt_w2 : fp32 -> bf16 weight conversion into d_ws (6 MB)
//  k_router            : per-atom dense gate vector [8] (top-2 scores, shared=1)
//  k_moe_main          : fused per-64-atom-tile MFMA kernel, loops all 8 experts,
//                        gate folded into H so zero-gate experts contribute 0.

typedef __attribute__((ext_vector_type(8))) short short8;   // 8 x bf16 (4 VGPRs)
typedef __attribute__((ext_vector_type(4))) float f32x4;    // MFMA accumulator

#define IN_F 512
#define HID  512
#define OUT_F 256
#define NEXP 8   // 6 routed + 2 shared

__device__ inline unsigned short f2bf(float f) {
    __hip_bfloat16 h = __float2bfloat16(f);
    return *reinterpret_cast<unsigned short*>(&h);
}

// ---------- weight conversion ----------
__global__ void k_cvt_w1(const float* __restrict__ rW1, const float* __restrict__ sW1,
                         unsigned short* __restrict__ dst) {
    int i = blockIdx.x * 256 + threadIdx.x;          // < 8*512*512
    int e = i >> 18;
    int off = i & ((1 << 18) - 1);
    float v = (e < 6) ? rW1[(size_t)e * 262144 + off]
                      : sW1[(size_t)(e - 6) * 262144 + off];
    dst[i] = f2bf(v);
}

__global__ void k_cvt_w2(const float* __restrict__ rW2, const float* __restrict__ sW2,
                         unsigned short* __restrict__ dst) {
    int i = blockIdx.x * 256 + threadIdx.x;          // < 8*256*512
    int e = i >> 17;
    int off = i & ((1 << 17) - 1);
    float v = (e < 6) ? rW2[(size_t)e * 131072 + off]
                      : sW2[(size_t)(e - 6) * 131072 + off];
    dst[i] = f2bf(v);
}

// ---------- router: dense gates [N][8] ----------
__global__ void k_router(const int* __restrict__ species, const float* __restrict__ emb,
                         const float* __restrict__ Wr, float* __restrict__ gates, int N) {
    int i = blockIdx.x * 256 + threadIdx.x;
    if (i >= N) return;
    int z = species[i];
    float u[16];
#pragma unroll
    for (int k = 0; k < 16; ++k) {
        float v = emb[z * 16 + k];
        u[k] = v / (1.f + __expf(-v));               // silu
    }
    float s[6];
    float mx = -1e30f;
#pragma unroll
    for (int e = 0; e < 6; ++e) {
        float a = 0.f;
#pragma unroll
        for (int k = 0; k < 16; ++k) a += u[k] * Wr[e * 16 + k];
        s[e] = a;
        mx = fmaxf(mx, a);
    }
    float sum = 0.f;
#pragma unroll
    for (int e = 0; e < 6; ++e) { s[e] = __expf(s[e] - mx); sum += s[e]; }
    float inv = 1.f / sum;
    // top-2 (stable: first index wins ties, matching jax top_k)
    int i0 = 0;
#pragma unroll
    for (int e = 1; e < 6; ++e) if (s[e] > s[i0]) i0 = e;
    int i1 = (i0 == 0) ? 1 : 0;
#pragma unroll
    for (int e = 0; e < 6; ++e) if (e != i0 && s[e] > s[i1]) i1 = e;
#pragma unroll
    for (int e = 0; e < 6; ++e)
        gates[(size_t)i * NEXP + e] = (e == i0 || e == i1) ? s[e] * inv : 0.f;
    gates[(size_t)i * NEXP + 6] = 1.f;
    gates[(size_t)i * NEXP + 7] = 1.f;
}

// ---------- fused MoE MLP ----------
// block = 256 threads (4 waves), tile = 64 atoms.
// LDS: xs 64x520 bf16 (66.5 KB) + hs 64x520 bf16 (66.5 KB) + gs 8x64 f32 (2 KB)
__global__ __launch_bounds__(256) void k_moe_main(
    const float* __restrict__ X,                 // [N,512] fp32
    const unsigned short* __restrict__ W1all,    // [8][512][512] bf16
    const unsigned short* __restrict__ W2all,    // [8][256][512] bf16
    const float* __restrict__ gates,             // [N][8]
    const float* __restrict__ rb1, const float* __restrict__ rb2,
    const float* __restrict__ sb1, const float* __restrict__ sb2,
    float* __restrict__ Y, int N)
{
    __shared__ unsigned short xs[64][520];
    __shared__ unsigned short hs[64][520];
    __shared__ float gs[NEXP][64];

    const int tid = threadIdx.x;
    const int row0 = blockIdx.x * 64;

    // stage X tile (fp32 -> bf16), zero-pad rows past N
    for (int i = tid; i < 64 * 128; i += 256) {
        int r = i >> 7;        // row 0..63
        int c4 = i & 127;      // float4 index 0..127
        int gr = row0 + r;
        float4 v = make_float4(0.f, 0.f, 0.f, 0.f);
        if (gr < N) v = reinterpret_cast<const float4*>(X + (size_t)gr * IN_F)[c4];
        ushort4 pk;
        pk.x = f2bf(v.x); pk.y = f2bf(v.y); pk.z = f2bf(v.z); pk.w = f2bf(v.w);
        *reinterpret_cast<ushort4*>(&xs[r][c4 * 4]) = pk;
    }
    // stage gates
    for (int i = tid; i < NEXP * 64; i += 256) {
        int e = i >> 6, m = i & 63;
        int gr = row0 + m;
        gs[e][m] = (gr < N) ? gates[(size_t)gr * NEXP + e] : 0.f;
    }
    __syncthreads();

    const int wv = tid >> 6;        // wave 0..3
    const int lane = tid & 63;
    const int quad = lane >> 4;     // 0..3
    const int l16 = lane & 15;      // 0..15

    f32x4 outacc[4][4] = {};        // persistent 64x64 C-tile per wave (cols wv*64..)

    for (int e = 0; e < NEXP; ++e) {
        const unsigned short* W1 = W1all + (size_t)e * HID * IN_F;   // [h][d]
        const unsigned short* W2 = W2all + (size_t)e * OUT_F * HID;  // [o][h]
        const float* b1 = (e < 6) ? rb1 + e * HID  : sb1 + (e - 6) * HID;
        const float* b2 = (e < 6) ? rb2 + e * OUT_F : sb2 + (e - 6) * OUT_F;

        // ---- phase A: H' = gate * silu(X @ W1^T + b1), cols [128*wv, 128*wv+128)
        for (int nc = 0; nc < 2; ++nc) {
            const int colbase = wv * 128 + nc * 64;
            f32x4 acc[4][4] = {};
            for (int kk = 0; kk < IN_F; kk += 32) {
                short8 af[4], bfr[4];
#pragma unroll
                for (int mt = 0; mt < 4; ++mt)
                    af[mt] = *reinterpret_cast<const short8*>(&xs[mt * 16 + l16][kk + quad * 8]);
#pragma unroll
                for (int nt = 0; nt < 4; ++nt) {
                    int wrow = colbase + nt * 16 + l16;
                    bfr[nt] = *reinterpret_cast<const short8*>(&W1[(size_t)wrow * IN_F + kk + quad * 8]);
                }
#pragma unroll
                for (int mt = 0; mt < 4; ++mt)
#pragma unroll
                    for (int nt = 0; nt < 4; ++nt)
                        acc[mt][nt] = __builtin_amdgcn_mfma_f32_16x16x32_bf16(
                            af[mt], bfr[nt], acc[mt][nt], 0, 0, 0);
            }
            // epilogue: +b1, silu, scale by gate, store bf16 to hs
#pragma unroll
            for (int mt = 0; mt < 4; ++mt) {
#pragma unroll
                for (int nt = 0; nt < 4; ++nt) {
                    int col = colbase + nt * 16 + l16;
                    float bb = b1[col];
#pragma unroll
                    for (int r = 0; r < 4; ++r) {
                        int row = mt * 16 + quad * 4 + r;
                        float v = acc[mt][nt][r] + bb;
                        float h = v / (1.f + __expf(-v));
                        hs[row][col] = f2bf(h * gs[e][row]);
                    }
                }
            }
        }
        __syncthreads();

        // ---- phase B: OUT += H' @ W2^T  (+ gate * b2), cols [64*wv, 64*wv+64)
        {
            const int colbase = wv * 64;
            for (int kk = 0; kk < HID; kk += 32) {
                short8 af[4], bfr[4];
#pragma unroll
                for (int mt = 0; mt < 4; ++mt)
                    af[mt] = *reinterpret_cast<const short8*>(&hs[mt * 16 + l16][kk + quad * 8]);
#pragma unroll
                for (int nt = 0; nt < 4; ++nt) {
                    int wrow = colbase + nt * 16 + l16;
                    bfr[nt] = *reinterpret_cast<const short8*>(&W2[(size_t)wrow * HID + kk + quad * 8]);
                }
#pragma unroll
                for (int mt = 0; mt < 4; ++mt)
#pragma unroll
                    for (int nt = 0; nt < 4; ++nt)
                        outacc[mt][nt] = __builtin_amdgcn_mfma_f32_16x16x32_bf16(
                            af[mt], bfr[nt], outacc[mt][nt], 0, 0, 0);
            }
#pragma unroll
            for (int mt = 0; mt < 4; ++mt)
#pragma unroll
                for (int nt = 0; nt < 4; ++nt) {
                    int col = colbase + nt * 16 + l16;
                    float bb = b2[col];
#pragma unroll
                    for (int r = 0; r < 4; ++r) {
                        int row = mt * 16 + quad * 4 + r;
                        outacc[mt][nt][r] += gs[e][row] * bb;
                    }
                }
        }
        __syncthreads();
    }

    // write OUT tile
#pragma unroll
    for (int mt = 0; mt < 4; ++mt)
#pragma unroll
        for (int nt = 0; nt < 4; ++nt)
#pragma unroll
            for (int r = 0; r < 4; ++r) {
                int row = mt * 16 + quad * 4 + r;
                int grow = row0 + row;
                if (grow < N) {
                    int col = wv * 64 + nt * 16 + l16;
                    Y[(size_t)grow * OUT_F + col] = outacc[mt][nt][r];
                }
            }
}

extern "C" void kernel_launch(void* const* d_in, const int* in_sizes, int n_in,
                              void* d_out, int out_size, void* d_ws, size_t ws_size,
                              hipStream_t stream) {
    const float* X       = (const float*)d_in[0];
    const int*   species = (const int*)d_in[1];
    const float* emb     = (const float*)d_in[2];
    const float* Wr      = (const float*)d_in[3];
    const float* rW1     = (const float*)d_in[4];
    const float* rb1     = (const float*)d_in[5];
    const float* rW2     = (const float*)d_in[6];
    const float* rb2     = (const float*)d_in[7];
    const float* sW1     = (const float*)d_in[8];
    const float* sb1     = (const float*)d_in[9];
    const float* sW2     = (const float*)d_in[10];
    const float* sb2     = (const float*)d_in[11];
    float* Y = (float*)d_out;
    const int N = in_sizes[1];   // species_idx count = n atoms

    // workspace layout: [w1 bf16: 4 MiB][w2 bf16: 2 MiB][gates: N*8*4 B]
    char* ws = (char*)d_ws;
    unsigned short* w1bf = (unsigned short*)ws;
    unsigned short* w2bf = (unsigned short*)(ws + (size_t)NEXP * HID * IN_F * 2);
    float* gates = (float*)(ws + (size_t)NEXP * HID * IN_F * 2 + (size_t)NEXP * OUT_F * HID * 2);

    k_cvt_w1<<<(NEXP * HID * IN_F) / 256, 256, 0, stream>>>(rW1, sW1, w1bf);
    k_cvt_w2<<<(NEXP * OUT_F * HID) / 256, 256, 0, stream>>>(rW2, sW2, w2bf);
    k_router<<<(N + 255) / 256, 256, 0, stream>>>(species, emb, Wr, gates, N);
    k_moe_main<<<(N + 63) / 64, 256, 0, stream>>>(X, w1bf, w2bf, gates,
                                                  rb1, rb2, sb1, sb2, Y, N);
}